// Round 1
// baseline (2256.068 us; speedup 1.0000x reference)
//
#include <hip/hip_runtime.h>
#include <hip/hip_bf16.h>
#include <math.h>

// Problem constants
#define BB 4
#define CC 128
#define HH 128
#define WW 128
#define HW (HH * WW)
#define DG 2
#define KK 9
#define OFFC (3 * DG * KK)   // 54
#define EPSV 1e-5f

// ---------------------------------------------------------------------------
// Weight repack kernels: make inner-loop weight reads contiguous + uniform.
// ---------------------------------------------------------------------------

// [OCH][128][9] -> [128 c][OCH][9]
template<int OCH>
__global__ void repack3x3_k(const float* __restrict__ wsrc, float* __restrict__ wdst) {
    int t = blockIdx.x * 256 + threadIdx.x;
    if (t >= OCH * CC * 9) return;
    int o = t / (CC * 9);
    int r = t - o * (CC * 9);
    int c = r / 9;
    int tap = r - c * 9;
    wdst[(c * OCH + o) * 9 + tap] = wsrc[t];
}

// dc_w [128 o][128 ci][9 k] (ci = d*64+c) -> [d][k][c][o]
__global__ void repack_dc_k(const float* __restrict__ wsrc, float* __restrict__ wdst) {
    int t = blockIdx.x * 256 + threadIdx.x;
    if (t >= CC * CC * 9) return;
    int o = t / (CC * 9);
    int r = t - o * (CC * 9);
    int ci = r / 9;
    int k = r - ci * 9;
    int d = ci >> 6;
    int c = ci & 63;
    wdst[((d * 9 + k) * 64 + c) * CC + o] = wsrc[t];
}

// cv2_w [128 o][128 c] -> [c][o]
__global__ void repack_1x1_k(const float* __restrict__ wsrc, float* __restrict__ wdst) {
    int t = blockIdx.x * 256 + threadIdx.x;
    if (t >= CC * CC) return;
    int o = t >> 7;
    int c = t & 127;
    wdst[c * CC + o] = wsrc[t];
}

// ---------------------------------------------------------------------------
// 3x3 conv, register-blocked: thread = (pixel w, group of OG output chans).
// grid = (H, B, OCH/(2*OG)), block = 256 (w = tid&127, sub-group = tid>>7).
// MODE 0: +bias               (offset conv)
// MODE 1: +bias, BN, ReLU     (resblock conv1)
// MODE 2: +bias, BN, +res, ReLU (resblock conv2)
// ---------------------------------------------------------------------------
template<int OCH, int OG, int MODE>
__global__ __launch_bounds__(256)
void conv3x3_k(const float* __restrict__ in, const float* __restrict__ wpk,
               const float* __restrict__ bias, const float* __restrict__ bnp,
               const float* __restrict__ res, float* __restrict__ out)
{
    const int w = threadIdx.x & 127;
    const int og = __builtin_amdgcn_readfirstlane((int)(blockIdx.z * 2 + (threadIdx.x >> 7)));
    const int h = blockIdx.x;
    const int b = blockIdx.y;

    const float* inb = in + (size_t)b * CC * HW;
    float acc[OG];
#pragma unroll
    for (int o = 0; o < OG; ++o) acc[o] = 0.f;

    const int hm = h - 1;
    for (int c = 0; c < CC; ++c) {
        const float* pc = inb + (size_t)c * HW;
        float ir[9];
#pragma unroll
        for (int dy = 0; dy < 3; ++dy) {
            int hh = hm + dy;
            bool rok = ((unsigned)hh < (unsigned)HH);
#pragma unroll
            for (int dx = 0; dx < 3; ++dx) {
                int ww = w + dx - 1;
                bool ok = rok && ((unsigned)ww < (unsigned)WW);
                ir[dy * 3 + dx] = ok ? pc[hh * WW + ww] : 0.f;
            }
        }
        const float* wc = wpk + ((size_t)c * OCH + og * OG) * 9;
#pragma unroll
        for (int o = 0; o < OG; ++o) {
#pragma unroll
            for (int t = 0; t < 9; ++t)
                acc[o] = fmaf(wc[o * 9 + t], ir[t], acc[o]);
        }
    }

    const int pix = h * WW + w;
#pragma unroll
    for (int o = 0; o < OG; ++o) {
        int oc = og * OG + o;
        float v = acc[o] + bias[oc];
        if (MODE >= 1) {
            float g = bnp[oc], be = bnp[CC + oc], m = bnp[2 * CC + oc], var = bnp[3 * CC + oc];
            float inv = g * rsqrtf(var + EPSV);
            v = v * inv + (be - m * inv);
        }
        if (MODE == 2) v += res[((size_t)(b * CC + oc)) * HW + pix];
        if (MODE >= 1) v = fmaxf(v, 0.f);
        out[((size_t)(b * OCH + oc)) * HW + pix] = v;
    }
}

// ---------------------------------------------------------------------------
// Modulated deformable conv + bias + BN(bn1) + LeakyReLU(0.1).
// grid = (H, B, 2), block 256: thread = (pixel w, group of 32 out chans).
// ---------------------------------------------------------------------------
__global__ __launch_bounds__(256)
void deform_k(const float* __restrict__ src_all, const float* __restrict__ off,
              const float* __restrict__ wpd, const float* __restrict__ dcb,
              const float* __restrict__ bnp, float* __restrict__ out)
{
    const int w = threadIdx.x & 127;
    const int og = __builtin_amdgcn_readfirstlane((int)(blockIdx.z * 2 + (threadIdx.x >> 7)));
    const int h = blockIdx.x;
    const int b = blockIdx.y;
    const int pix = h * WW + w;

    float acc[32];
#pragma unroll
    for (int o = 0; o < 32; ++o) acc[o] = 0.f;

    const float* offb = off + (size_t)b * OFFC * HW;

    for (int d = 0; d < DG; ++d) {
        const float* src = src_all + ((size_t)b * CC + d * 64) * HW;
        for (int k = 0; k < KK; ++k) {
            float oy = offb[(size_t)(d * 18 + 2 * k) * HW + pix];
            float ox = offb[(size_t)(d * 18 + 2 * k + 1) * HW + pix];
            float mz = offb[(size_t)(36 + d * 9 + k) * HW + pix];
            float ms = 1.f / (1.f + expf(-mz));

            float py = oy + (float)h + (float)(k / 3 - 1);
            float px = ox + (float)w + (float)(k % 3 - 1);
            float y0f = floorf(py), x0f = floorf(px);
            float fy = py - y0f, fx = px - x0f;
            int y0 = (int)y0f, x0 = (int)x0f;
            int y1 = y0 + 1, x1 = x0 + 1;
            float vy0 = ((unsigned)y0 < (unsigned)HH) ? 1.f : 0.f;
            float vy1 = ((unsigned)y1 < (unsigned)HH) ? 1.f : 0.f;
            float vx0 = ((unsigned)x0 < (unsigned)WW) ? 1.f : 0.f;
            float vx1 = ((unsigned)x1 < (unsigned)WW) ? 1.f : 0.f;
            float w00 = (1.f - fy) * (1.f - fx) * vy0 * vx0 * ms;
            float w01 = (1.f - fy) * fx * vy0 * vx1 * ms;
            float w10 = fy * (1.f - fx) * vy1 * vx0 * ms;
            float w11 = fy * fx * vy1 * vx1 * ms;
            int y0c = min(max(y0, 0), HH - 1), y1c = min(max(y1, 0), HH - 1);
            int x0c = min(max(x0, 0), WW - 1), x1c = min(max(x1, 0), WW - 1);
            int i00 = y0c * WW + x0c, i01 = y0c * WW + x1c;
            int i10 = y1c * WW + x0c, i11 = y1c * WW + x1c;

            const float* wk = wpd + (size_t)((d * 9 + k) * 64) * CC + og * 32;
            for (int c = 0; c < 64; ++c) {
                const float* sc_ = src + (size_t)c * HW;
                float v = w00 * sc_[i00] + w01 * sc_[i01] + w10 * sc_[i10] + w11 * sc_[i11];
                const float* wr = wk + (size_t)c * CC;
#pragma unroll
                for (int o = 0; o < 32; ++o)
                    acc[o] = fmaf(wr[o], v, acc[o]);
            }
        }
    }

#pragma unroll
    for (int o = 0; o < 32; ++o) {
        int oc = og * 32 + o;
        float v = acc[o] + dcb[oc];
        float g = bnp[oc], be = bnp[CC + oc], m = bnp[2 * CC + oc], var = bnp[3 * CC + oc];
        float inv = g * rsqrtf(var + EPSV);
        v = v * inv + (be - m * inv);
        v = (v > 0.f) ? v : 0.1f * v;
        out[((size_t)(b * CC + oc)) * HW + pix] = v;
    }
}

// ---------------------------------------------------------------------------
// 1x1 conv (no bias) + BN(bn2) + LeakyReLU(0.1) + residual add (x).
// ---------------------------------------------------------------------------
__global__ __launch_bounds__(256)
void conv1x1_k(const float* __restrict__ in, const float* __restrict__ wpc,
               const float* __restrict__ bnp, const float* __restrict__ res,
               float* __restrict__ out)
{
    const int w = threadIdx.x & 127;
    const int og = __builtin_amdgcn_readfirstlane((int)(blockIdx.z * 2 + (threadIdx.x >> 7)));
    const int h = blockIdx.x;
    const int b = blockIdx.y;
    const int pix = h * WW + w;

    float acc[32];
#pragma unroll
    for (int o = 0; o < 32; ++o) acc[o] = 0.f;

    const float* inb = in + (size_t)b * CC * HW;
    for (int c = 0; c < CC; ++c) {
        float v = inb[(size_t)c * HW + pix];
        const float* wr = wpc + c * CC + og * 32;
#pragma unroll
        for (int o = 0; o < 32; ++o)
            acc[o] = fmaf(wr[o], v, acc[o]);
    }

#pragma unroll
    for (int o = 0; o < 32; ++o) {
        int oc = og * 32 + o;
        float g = bnp[oc], be = bnp[CC + oc], m = bnp[2 * CC + oc], var = bnp[3 * CC + oc];
        float inv = g * rsqrtf(var + EPSV);
        float v = acc[o] * inv + (be - m * inv);
        v = (v > 0.f) ? v : 0.1f * v;
        v += res[((size_t)(b * CC + oc)) * HW + pix];
        out[((size_t)(b * CC + oc)) * HW + pix] = v;
    }
}

// ---------------------------------------------------------------------------
extern "C" void kernel_launch(void* const* d_in, const int* in_sizes, int n_in,
                              void* d_out, int out_size, void* d_ws, size_t ws_size,
                              hipStream_t stream) {
    const float* x      = (const float*)d_in[0];
    const float* rb_w1  = (const float*)d_in[1];
    const float* rb_b1  = (const float*)d_in[2];
    const float* rb_bn1 = (const float*)d_in[3];
    const float* rb_w2  = (const float*)d_in[4];
    const float* rb_b2  = (const float*)d_in[5];
    const float* rb_bn2 = (const float*)d_in[6];
    const float* off_w  = (const float*)d_in[7];
    const float* off_b  = (const float*)d_in[8];
    const float* dc_w   = (const float*)d_in[9];
    const float* dc_b   = (const float*)d_in[10];
    const float* bn1    = (const float*)d_in[11];
    const float* cv2_w  = (const float*)d_in[12];
    const float* bn2    = (const float*)d_in[13];

    float* ws  = (float*)d_ws;
    float* wp1 = ws;                    // 147456
    float* wp2 = wp1 + CC * CC * 9;     // 147456
    float* wpo = wp2 + CC * CC * 9;     // 62208
    float* wpd = wpo + OFFC * CC * 9;   // 147456
    float* wpc = wpd + CC * CC * 9;     // 16384
    float* h1  = wpc + CC * CC;         // 8388608
    float* h2  = h1 + (size_t)BB * CC * HW;  // 8388608
    float* off = h2 + (size_t)BB * CC * HW;  // 3538944
    float* h3  = h1;  // h1 dead after offset conv; alias to save workspace

    // weight repacks (cheap, run every call for graph-capture safety)
    repack3x3_k<CC><<<(CC * CC * 9 + 255) / 256, 256, 0, stream>>>(rb_w1, wp1);
    repack3x3_k<CC><<<(CC * CC * 9 + 255) / 256, 256, 0, stream>>>(rb_w2, wp2);
    repack3x3_k<OFFC><<<(OFFC * CC * 9 + 255) / 256, 256, 0, stream>>>(off_w, wpo);
    repack_dc_k<<<(CC * CC * 9 + 255) / 256, 256, 0, stream>>>(dc_w, wpd);
    repack_1x1_k<<<(CC * CC + 255) / 256, 256, 0, stream>>>(cv2_w, wpc);

    dim3 blk(256, 1, 1);
    dim3 grid2(HH, BB, 2);   // 128-out-channel kernels: 4 groups of 32
    dim3 grid1(HH, BB, 1);   // 54-out-channel offset conv: 2 groups of 27

    // ResBlock
    conv3x3_k<CC, 32, 1><<<grid2, blk, 0, stream>>>(x, wp1, rb_b1, rb_bn1, nullptr, h1);
    conv3x3_k<CC, 32, 2><<<grid2, blk, 0, stream>>>(h1, wp2, rb_b2, rb_bn2, x, h2);
    // offset conv
    conv3x3_k<OFFC, 27, 0><<<grid1, blk, 0, stream>>>(h2, wpo, off_b, nullptr, nullptr, off);
    // modulated deformable conv + BN + LeakyReLU
    deform_k<<<grid2, blk, 0, stream>>>(h2, off, wpd, dc_b, bn1, h3);
    // 1x1 conv + BN + LeakyReLU + residual
    conv1x1_k<<<grid2, blk, 0, stream>>>(h3, wpc, bn2, x, (float*)d_out);
}

// Round 2
// 363.896 us; speedup vs baseline: 6.1998x; 6.1998x over previous
//
#include <hip/hip_runtime.h>
#include <math.h>

#define BB 4
#define EPSV 1e-5f

typedef __attribute__((ext_vector_type(8))) short short8;
typedef __attribute__((ext_vector_type(4))) float floatx4;
typedef __attribute__((ext_vector_type(4))) unsigned short ushort4v;

__device__ inline float b2f(unsigned short u) {
    unsigned v = ((unsigned)u) << 16;
    return __builtin_bit_cast(float, v);
}
__device__ inline unsigned short f2b(float f) {
    unsigned u = __builtin_bit_cast(unsigned, f);
    u += 0x7FFFu + ((u >> 16) & 1u);   // RNE
    return (unsigned short)(u >> 16);
}

// ---------------------------------------------------------------------------
// x [B][128 c][16384 px] fp32  ->  xb [B][16384 px][128 c] bf16  (NHWC)
// ---------------------------------------------------------------------------
__global__ __launch_bounds__(256) void transpose_k(const float* __restrict__ x,
                                                   unsigned short* __restrict__ xb) {
    __shared__ unsigned short t[64][136];
    const int tid = threadIdx.x;
    const int px0 = blockIdx.x * 64;
    const int b = blockIdx.y;
    const int pxr = tid & 63;
    const int c0 = tid >> 6;
#pragma unroll
    for (int i = 0; i < 32; ++i) {
        int c = c0 + i * 4;
        float v = x[(((size_t)b * 128 + c) << 14) + px0 + pxr];
        t[pxr][c] = f2b(v);
    }
    __syncthreads();
#pragma unroll
    for (int i = 0; i < 4; ++i) {
        int idx = tid + i * 256;
        int px = idx >> 4;
        int c8 = idx & 15;
        short8 v = *(const short8*)&t[px][c8 * 8];
        *(short8*)&xb[(((size_t)b << 14) + px0 + px) * 128 + c8 * 8] = v;
    }
}

// ---------------------------------------------------------------------------
// Weight repacks into MFMA A-fragment order:
// dst[((step*NMT2 + mt)*64 + lane)*8 + j] = W[oc = mt*16 + (lane&15)]
//                                            [k  = step*32 + (lane>>4)*8 + j]
// ---------------------------------------------------------------------------
// conv 3x3: k = tap*128 + c, src [OCH][128][9]
template<int MPAD, int OCH>
__global__ __launch_bounds__(256) void repack_conv_frag(const float* __restrict__ w,
                                                        unsigned short* __restrict__ dst) {
    int t = blockIdx.x * 256 + threadIdx.x;
    if (t >= 1152 * MPAD) return;
    const int NMT2 = MPAD / 16;
    int j = t & 7, lane = (t >> 3) & 63, rest = t >> 9;
    int mt = rest % NMT2, step = rest / NMT2;
    int oc = mt * 16 + (lane & 15);
    int k = step * 32 + ((lane >> 4) << 3) + j;
    int tap = k >> 7, c = k & 127;
    float v = (oc < OCH) ? w[((size_t)oc * 128 + c) * 9 + tap] : 0.f;
    dst[t] = f2b(v);
}

// dc: k = dk*64 + c, dk = d*9+kk, src [128 oc][128 ci=d*64+c][9 kk]
__global__ __launch_bounds__(256) void repack_dc_frag(const float* __restrict__ w,
                                                      unsigned short* __restrict__ dst) {
    int t = blockIdx.x * 256 + threadIdx.x;
    if (t >= 1152 * 128) return;
    int j = t & 7, lane = (t >> 3) & 63, rest = t >> 9;
    int mt = rest & 7, step = rest >> 3;
    int oc = mt * 16 + (lane & 15);
    int k = step * 32 + ((lane >> 4) << 3) + j;
    int dk = k >> 6, c = k & 63;
    int d = (dk >= 9) ? 1 : 0;
    int kk = dk - d * 9;
    float v = w[((size_t)oc * 128 + d * 64 + c) * 9 + kk];
    dst[t] = f2b(v);
}

// cv2 1x1: k = c, src [128 oc][128 c]
__global__ __launch_bounds__(256) void repack_cv2_frag(const float* __restrict__ w,
                                                       unsigned short* __restrict__ dst) {
    int t = blockIdx.x * 256 + threadIdx.x;
    if (t >= 128 * 128) return;
    int j = t & 7, lane = (t >> 3) & 63, rest = t >> 9;
    int mt = rest & 7, step = rest >> 3;
    int oc = mt * 16 + (lane & 15);
    int k = step * 32 + ((lane >> 4) << 3) + j;
    dst[t] = f2b(w[oc * 128 + k]);
}

// ---------------------------------------------------------------------------
// 3x3 conv, implicit GEMM via MFMA.
// Block = (2*NMT*16) oc x 64 px (half a row). 4 waves: wm = wid&1, wn = wid>>1.
// LDS: 3 input rows x 66 w x 128 c (c-stride 136 for 16B alignment).
// K-order: k = tap*128 + c; 36 K-steps of 32.
// MODE 0: +bias -> fp32 [B][HW][54]        (offset conv, MPAD=64)
// MODE 1: +bias,BN,ReLU -> bf16 NHWC        (rb conv1)
// MODE 2: +bias,BN,+x(NCHW fp32),ReLU -> bf16 NHWC (rb conv2)
// ---------------------------------------------------------------------------
template<int NMT, int MODE>
__global__ __launch_bounds__(256, 2) void conv3x3_mfma(
    const unsigned short* __restrict__ in, const unsigned short* __restrict__ wf,
    const float* __restrict__ bias, const float* __restrict__ bnp,
    const float* __restrict__ res, void* __restrict__ outv)
{
    __shared__ unsigned short sm[3][66][136];
    const int tid = threadIdx.x;
    const int lane = tid & 63, wid = tid >> 6;
    const int wm = wid & 1, wn = wid >> 1;
    const int w0 = (blockIdx.x & 1) * 64;
    const int h = blockIdx.x >> 1;
    const int b = blockIdx.y;

    // stage 3 rows x 66 w x 128 c, zero-filled at borders
    for (int idx = tid; idx < 3168; idx += 256) {
        int r = idx / 1056, rem = idx - r * 1056;
        int wl = rem >> 4, c8 = rem & 15;
        int hh = h - 1 + r, ww = w0 - 1 + wl;
        short8 v = {0, 0, 0, 0, 0, 0, 0, 0};
        if ((unsigned)hh < 128u && (unsigned)ww < 128u)
            v = *(const short8*)&in[(((size_t)b << 14) + hh * 128 + ww) * 128 + c8 * 8];
        *(short8*)&sm[r][wl][c8 * 8] = v;
    }
    __syncthreads();

    floatx4 acc[NMT][2];
#pragma unroll
    for (int mt = 0; mt < NMT; ++mt)
#pragma unroll
        for (int nt = 0; nt < 2; ++nt)
            acc[mt][nt] = (floatx4){0.f, 0.f, 0.f, 0.f};

    const int n16 = lane & 15, quad = lane >> 4;
#pragma unroll
    for (int tap = 0; tap < 9; ++tap) {
        const int ky = tap / 3, kx = tap % 3;
#pragma unroll
        for (int cc = 0; cc < 4; ++cc) {
            const int step = tap * 4 + cc;
            short8 a[NMT], bf[2];
#pragma unroll
            for (int nt = 0; nt < 2; ++nt)
                bf[nt] = *(const short8*)&sm[ky][wn * 32 + nt * 16 + n16 + kx][cc * 32 + quad * 8];
#pragma unroll
            for (int mt = 0; mt < NMT; ++mt)
                a[mt] = *(const short8*)&wf[((size_t)(step * (2 * NMT) + wm * NMT + mt) * 64 + lane) * 8];
#pragma unroll
            for (int mt = 0; mt < NMT; ++mt)
#pragma unroll
                for (int nt = 0; nt < 2; ++nt)
                    acc[mt][nt] = __builtin_amdgcn_mfma_f32_16x16x32_bf16(a[mt], bf[nt], acc[mt][nt], 0, 0, 0);
        }
    }

    // epilogue
#pragma unroll
    for (int mt = 0; mt < NMT; ++mt) {
        const int ocb = (wm * NMT + mt) * 16 + quad * 4;
        float Ae[4], Bе[4];
#pragma unroll
        for (int r = 0; r < 4; ++r) {
            int oc = ocb + r;
            if (MODE == 0) {
                Ae[r] = 1.f;
                Bе[r] = (oc < 54) ? bias[oc] : 0.f;
            } else {
                float g = bnp[oc], be = bnp[128 + oc], m = bnp[256 + oc], vv = bnp[384 + oc];
                float inv = g * rsqrtf(vv + EPSV);
                Ae[r] = inv;
                Bе[r] = be - m * inv + bias[oc] * inv;
            }
        }
#pragma unroll
        for (int nt = 0; nt < 2; ++nt) {
            int pxg = h * 128 + w0 + wn * 32 + nt * 16 + n16;
            if (MODE == 0) {
                float* outf = (float*)outv;
#pragma unroll
                for (int r = 0; r < 4; ++r) {
                    int oc = ocb + r;
                    if (oc < 54)
                        outf[((size_t)(b << 14) + pxg) * 54 + oc] = acc[mt][nt][r] + Bе[r];
                }
            } else {
                ushort4v pk;
#pragma unroll
                for (int r = 0; r < 4; ++r) {
                    float v = acc[mt][nt][r] * Ae[r] + Bе[r];
                    if (MODE == 2) v += res[(((size_t)b * 128 + ocb + r) << 14) + pxg];
                    v = fmaxf(v, 0.f);
                    pk[r] = f2b(v);
                }
                *(ushort4v*)&((unsigned short*)outv)[((size_t)((b << 14) + pxg)) * 128 + ocb] = pk;
            }
        }
    }
}

// ---------------------------------------------------------------------------
// Fused modulated deformable conv:
// per (d,k) pair, sample 64 px x 64 c bilinear tile (mask folded into corner
// weights) into LDS, then 2 MFMA K-steps. Epilogue: +dc_b, BN(bn1), LeakyReLU.
// Block = 128 oc x 64 px; K = 18 dk * 64 c = 36 steps.
// ---------------------------------------------------------------------------
__global__ __launch_bounds__(256, 2) void deform_mfma(
    const unsigned short* __restrict__ src, const float* __restrict__ off,
    const unsigned short* __restrict__ wf, const float* __restrict__ dcb,
    const float* __restrict__ bnp, unsigned short* __restrict__ out)
{
    __shared__ unsigned short gt[64][72];
    const int tid = threadIdx.x;
    const int lane = tid & 63, wid = tid >> 6;
    const int wm = wid & 1, wn = wid >> 1;
    const int w0 = (blockIdx.x & 1) * 64;
    const int h = blockIdx.x >> 1;
    const int b = blockIdx.y;
    const int pxl = tid & 63;
    const int cgrp = tid >> 6;
    const int pxg = h * 128 + w0 + pxl;
    const float* offp = off + ((size_t)(b << 14) + pxg) * 54;
    const int n16 = lane & 15, quad = lane >> 4;

    floatx4 acc[4][2];
#pragma unroll
    for (int mt = 0; mt < 4; ++mt)
#pragma unroll
        for (int nt = 0; nt < 2; ++nt)
            acc[mt][nt] = (floatx4){0.f, 0.f, 0.f, 0.f};

    for (int dk = 0; dk < 18; ++dk) {
        const int d = (dk >= 9) ? 1 : 0;
        const int kk = dk - d * 9;
        float oy = offp[2 * dk], ox = offp[2 * dk + 1], mz = offp[36 + dk];
        float ms = 1.f / (1.f + __expf(-mz));
        float py = oy + (float)(pxg >> 7) + (float)(kk / 3 - 1);
        float pxs = ox + (float)(pxg & 127) + (float)(kk % 3 - 1);
        float y0f = floorf(py), x0f = floorf(pxs);
        float fy = py - y0f, fx = pxs - x0f;
        int y0 = (int)y0f, x0 = (int)x0f;
        int y1 = y0 + 1, x1 = x0 + 1;
        float w00 = (1.f - fy) * (1.f - fx) * ms, w01 = (1.f - fy) * fx * ms;
        float w10 = fy * (1.f - fx) * ms, w11 = fy * fx * ms;
        if ((unsigned)y0 >= 128u) { w00 = 0.f; w01 = 0.f; }
        if ((unsigned)y1 >= 128u) { w10 = 0.f; w11 = 0.f; }
        if ((unsigned)x0 >= 128u) { w00 = 0.f; w10 = 0.f; }
        if ((unsigned)x1 >= 128u) { w01 = 0.f; w11 = 0.f; }
        int y0c = min(max(y0, 0), 127), y1c = min(max(y1, 0), 127);
        int x0c = min(max(x0, 0), 127), x1c = min(max(x1, 0), 127);
        const unsigned short* p00 = src + (((size_t)(b << 14) + y0c * 128 + x0c) << 7) + d * 64;
        const unsigned short* p01 = src + (((size_t)(b << 14) + y0c * 128 + x1c) << 7) + d * 64;
        const unsigned short* p10 = src + (((size_t)(b << 14) + y1c * 128 + x0c) << 7) + d * 64;
        const unsigned short* p11 = src + (((size_t)(b << 14) + y1c * 128 + x1c) << 7) + d * 64;

#pragma unroll
        for (int cc2 = 0; cc2 < 2; ++cc2) {
            int c0 = (cgrp * 2 + cc2) * 8;
            short8 r00 = *(const short8*)(p00 + c0);
            short8 r01 = *(const short8*)(p01 + c0);
            short8 r10 = *(const short8*)(p10 + c0);
            short8 r11 = *(const short8*)(p11 + c0);
            short8 o;
#pragma unroll
            for (int j = 0; j < 8; ++j) {
                float v = w00 * b2f((unsigned short)r00[j]) + w01 * b2f((unsigned short)r01[j])
                        + w10 * b2f((unsigned short)r10[j]) + w11 * b2f((unsigned short)r11[j]);
                o[j] = (short)f2b(v);
            }
            *(short8*)&gt[pxl][c0] = o;
        }
        __syncthreads();
#pragma unroll
        for (int hf = 0; hf < 2; ++hf) {
            int s = dk * 2 + hf;
            short8 a[4], bfr[2];
#pragma unroll
            for (int nt = 0; nt < 2; ++nt)
                bfr[nt] = *(const short8*)&gt[wn * 32 + nt * 16 + n16][hf * 32 + quad * 8];
#pragma unroll
            for (int mt = 0; mt < 4; ++mt)
                a[mt] = *(const short8*)&wf[((size_t)(s * 8 + wm * 4 + mt) * 64 + lane) * 8];
#pragma unroll
            for (int mt = 0; mt < 4; ++mt)
#pragma unroll
                for (int nt = 0; nt < 2; ++nt)
                    acc[mt][nt] = __builtin_amdgcn_mfma_f32_16x16x32_bf16(a[mt], bfr[nt], acc[mt][nt], 0, 0, 0);
        }
        __syncthreads();
    }

#pragma unroll
    for (int mt = 0; mt < 4; ++mt) {
        const int ocb = (wm * 4 + mt) * 16 + quad * 4;
        float Ae[4], Bе[4];
#pragma unroll
        for (int r = 0; r < 4; ++r) {
            int oc = ocb + r;
            float g = bnp[oc], be = bnp[128 + oc], m = bnp[256 + oc], vv = bnp[384 + oc];
            float inv = g * rsqrtf(vv + EPSV);
            Ae[r] = inv;
            Bе[r] = be - m * inv + dcb[oc] * inv;
        }
#pragma unroll
        for (int nt = 0; nt < 2; ++nt) {
            int pxg2 = h * 128 + w0 + wn * 32 + nt * 16 + n16;
            ushort4v pk;
#pragma unroll
            for (int r = 0; r < 4; ++r) {
                float v = acc[mt][nt][r] * Ae[r] + Bе[r];
                v = (v > 0.f) ? v : 0.1f * v;
                pk[r] = f2b(v);
            }
            *(ushort4v*)&out[((size_t)((b << 14) + pxg2)) * 128 + ocb] = pk;
        }
    }
}

// ---------------------------------------------------------------------------
// 1x1 conv GEMM (K=128, B-frags straight from global NHWC) + BN(bn2) +
// LeakyReLU + residual x -> fp32 NCHW d_out.
// ---------------------------------------------------------------------------
__global__ __launch_bounds__(256, 2) void conv1x1_mfma(
    const unsigned short* __restrict__ in, const unsigned short* __restrict__ wf,
    const float* __restrict__ bnp, const float* __restrict__ x, float* __restrict__ out)
{
    const int tid = threadIdx.x;
    const int lane = tid & 63, wid = tid >> 6;
    const int wm = wid & 1, wn = wid >> 1;
    const int w0 = (blockIdx.x & 1) * 64;
    const int h = blockIdx.x >> 1;
    const int b = blockIdx.y;
    const int n16 = lane & 15, quad = lane >> 4;

    floatx4 acc[4][2];
#pragma unroll
    for (int mt = 0; mt < 4; ++mt)
#pragma unroll
        for (int nt = 0; nt < 2; ++nt)
            acc[mt][nt] = (floatx4){0.f, 0.f, 0.f, 0.f};

#pragma unroll
    for (int s = 0; s < 4; ++s) {
        short8 a[4], bfr[2];
#pragma unroll
        for (int nt = 0; nt < 2; ++nt) {
            int px = h * 128 + w0 + wn * 32 + nt * 16 + n16;
            bfr[nt] = *(const short8*)&in[((size_t)((b << 14) + px)) * 128 + s * 32 + quad * 8];
        }
#pragma unroll
        for (int mt = 0; mt < 4; ++mt)
            a[mt] = *(const short8*)&wf[((size_t)(s * 8 + wm * 4 + mt) * 64 + lane) * 8];
#pragma unroll
        for (int mt = 0; mt < 4; ++mt)
#pragma unroll
            for (int nt = 0; nt < 2; ++nt)
                acc[mt][nt] = __builtin_amdgcn_mfma_f32_16x16x32_bf16(a[mt], bfr[nt], acc[mt][nt], 0, 0, 0);
    }

#pragma unroll
    for (int mt = 0; mt < 4; ++mt) {
        const int ocb = (wm * 4 + mt) * 16 + quad * 4;
        float Ae[4], Bе[4];
#pragma unroll
        for (int r = 0; r < 4; ++r) {
            int oc = ocb + r;
            float g = bnp[oc], be = bnp[128 + oc], m = bnp[256 + oc], vv = bnp[384 + oc];
            float inv = g * rsqrtf(vv + EPSV);
            Ae[r] = inv;
            Bе[r] = be - m * inv;
        }
#pragma unroll
        for (int nt = 0; nt < 2; ++nt) {
            int pxg2 = h * 128 + w0 + wn * 32 + nt * 16 + n16;
#pragma unroll
            for (int r = 0; r < 4; ++r) {
                int oc = ocb + r;
                float v = acc[mt][nt][r] * Ae[r] + Bе[r];
                v = (v > 0.f) ? v : 0.1f * v;
                v += x[(((size_t)b * 128 + oc) << 14) + pxg2];
                out[(((size_t)b * 128 + oc) << 14) + pxg2] = v;
            }
        }
    }
}

// ---------------------------------------------------------------------------
extern "C" void kernel_launch(void* const* d_in, const int* in_sizes, int n_in,
                              void* d_out, int out_size, void* d_ws, size_t ws_size,
                              hipStream_t stream) {
    const float* x      = (const float*)d_in[0];
    const float* rb_w1  = (const float*)d_in[1];
    const float* rb_b1  = (const float*)d_in[2];
    const float* rb_bn1 = (const float*)d_in[3];
    const float* rb_w2  = (const float*)d_in[4];
    const float* rb_b2  = (const float*)d_in[5];
    const float* rb_bn2 = (const float*)d_in[6];
    const float* off_w  = (const float*)d_in[7];
    const float* off_b  = (const float*)d_in[8];
    const float* dc_w   = (const float*)d_in[9];
    const float* dc_b   = (const float*)d_in[10];
    const float* bn1    = (const float*)d_in[11];
    const float* cv2_w  = (const float*)d_in[12];
    const float* bn2    = (const float*)d_in[13];

    char* base = (char*)d_ws;
    const size_t TSZ = (size_t)4 * 16384 * 128 * 2;       // 16.78 MB bf16 tensor
    unsigned short* xb = (unsigned short*)base;            // aliased later as h3
    unsigned short* h1 = (unsigned short*)(base + TSZ);    // aliased later as off
    unsigned short* h2 = (unsigned short*)(base + 2 * TSZ);
    unsigned short* wf1 = (unsigned short*)(base + 3 * TSZ);
    unsigned short* wf2 = wf1 + 1152 * 128;
    unsigned short* wfO = wf2 + 1152 * 128;
    unsigned short* wfD = wfO + 1152 * 64;
    unsigned short* wfC = wfD + 1152 * 128;
    float* offb = (float*)h1;            // [B][HW][54] fp32, 14.16 MB <= TSZ
    unsigned short* h3 = xb;             // xb dead after conv1

    dim3 blk(256, 1, 1);
    dim3 grid(256, BB, 1);

    transpose_k<<<grid, blk, 0, stream>>>(x, xb);
    repack_conv_frag<128, 128><<<576, 256, 0, stream>>>(rb_w1, wf1);
    repack_conv_frag<128, 128><<<576, 256, 0, stream>>>(rb_w2, wf2);
    repack_conv_frag<64, 54><<<288, 256, 0, stream>>>(off_w, wfO);
    repack_dc_frag<<<576, 256, 0, stream>>>(dc_w, wfD);
    repack_cv2_frag<<<64, 256, 0, stream>>>(cv2_w, wfC);

    // ResBlock
    conv3x3_mfma<4, 1><<<grid, blk, 0, stream>>>(xb, wf1, rb_b1, rb_bn1, nullptr, (void*)h1);
    conv3x3_mfma<4, 2><<<grid, blk, 0, stream>>>(h1, wf2, rb_b2, rb_bn2, x, (void*)h2);
    // offset conv (writes over h1, which is dead)
    conv3x3_mfma<2, 0><<<grid, blk, 0, stream>>>(h2, wfO, off_b, nullptr, nullptr, (void*)offb);
    // fused modulated deformable conv + BN + LeakyReLU
    deform_mfma<<<grid, blk, 0, stream>>>(h2, offb, wfD, dc_b, bn1, h3);
    // 1x1 conv + BN + LeakyReLU + residual
    conv1x1_mfma<<<grid, blk, 0, stream>>>(h3, wfC, bn2, x, (float*)d_out);
}

// Round 3
// 304.516 us; speedup vs baseline: 7.4087x; 1.1950x over previous
//
#include <hip/hip_runtime.h>
#include <math.h>

#define BB 4
#define EPSV 1e-5f

typedef __attribute__((ext_vector_type(8))) short short8;
typedef __attribute__((ext_vector_type(4))) float floatx4;
typedef __attribute__((ext_vector_type(4))) unsigned short ushort4v;

__device__ inline float b2f(unsigned short u) {
    unsigned v = ((unsigned)u) << 16;
    return __builtin_bit_cast(float, v);
}
__device__ inline unsigned short f2b(float f) {
    unsigned u = __builtin_bit_cast(unsigned, f);
    u += 0x7FFFu + ((u >> 16) & 1u);   // RNE
    return (unsigned short)(u >> 16);
}

// ---------------------------------------------------------------------------
// x [B][128 c][16384 px] fp32  ->  xb [B][16384 px][128 c] bf16  (NHWC)
// ---------------------------------------------------------------------------
__global__ __launch_bounds__(256) void transpose_k(const float* __restrict__ x,
                                                   unsigned short* __restrict__ xb) {
    __shared__ unsigned short t[64][136];
    const int tid = threadIdx.x;
    const int px0 = blockIdx.x * 64;
    const int b = blockIdx.y;
    const int pxr = tid & 63;
    const int c0 = tid >> 6;
#pragma unroll
    for (int i = 0; i < 32; ++i) {
        int c = c0 + i * 4;
        float v = x[(((size_t)b * 128 + c) << 14) + px0 + pxr];
        t[pxr][c] = f2b(v);
    }
    __syncthreads();
#pragma unroll
    for (int i = 0; i < 4; ++i) {
        int idx = tid + i * 256;
        int px = idx >> 4;
        int c8 = idx & 15;
        short8 v = *(const short8*)&t[px][c8 * 8];
        *(short8*)&xb[(((size_t)b << 14) + px0 + px) * 128 + c8 * 8] = v;
    }
}

// ---------------------------------------------------------------------------
// Weight repacks into MFMA A-fragment order:
// dst[((step*NMT2 + mt)*64 + lane)*8 + j] = W[oc = mt*16 + (lane&15)]
//                                            [k  = step*32 + (lane>>4)*8 + j]
// ---------------------------------------------------------------------------
// conv 3x3 (ch-split K order): k = half*576 + tap*64 + c64, src [OCH][128][9]
template<int MPAD, int OCH>
__global__ __launch_bounds__(256) void repack_conv_frag(const float* __restrict__ w,
                                                        unsigned short* __restrict__ dst) {
    int t = blockIdx.x * 256 + threadIdx.x;
    if (t >= 1152 * MPAD) return;
    const int NMT2 = MPAD / 16;
    int j = t & 7, lane = (t >> 3) & 63, rest = t >> 9;
    int mt = rest % NMT2, step = rest / NMT2;
    int oc = mt * 16 + (lane & 15);
    int k = step * 32 + ((lane >> 4) << 3) + j;
    int half = k / 576;
    int tap = (k - half * 576) >> 6;
    int c = half * 64 + (k & 63);
    float v = (oc < OCH) ? w[((size_t)oc * 128 + c) * 9 + tap] : 0.f;
    dst[t] = f2b(v);
}

// dc: k = dk*64 + c, dk = d*9+kk, src [128 oc][128 ci=d*64+c][9 kk]
__global__ __launch_bounds__(256) void repack_dc_frag(const float* __restrict__ w,
                                                      unsigned short* __restrict__ dst) {
    int t = blockIdx.x * 256 + threadIdx.x;
    if (t >= 1152 * 128) return;
    int j = t & 7, lane = (t >> 3) & 63, rest = t >> 9;
    int mt = rest & 7, step = rest >> 3;
    int oc = mt * 16 + (lane & 15);
    int k = step * 32 + ((lane >> 4) << 3) + j;
    int dk = k >> 6, c = k & 63;
    int d = (dk >= 9) ? 1 : 0;
    int kk = dk - d * 9;
    float v = w[((size_t)oc * 128 + d * 64 + c) * 9 + kk];
    dst[t] = f2b(v);
}

// cv2 1x1: k = c, src [128 oc][128 c]
__global__ __launch_bounds__(256) void repack_cv2_frag(const float* __restrict__ w,
                                                       unsigned short* __restrict__ dst) {
    int t = blockIdx.x * 256 + threadIdx.x;
    if (t >= 128 * 128) return;
    int j = t & 7, lane = (t >> 3) & 63, rest = t >> 9;
    int mt = rest & 7, step = rest >> 3;
    int oc = mt * 16 + (lane & 15);
    int k = step * 32 + ((lane >> 4) << 3) + j;
    dst[t] = f2b(w[oc * 128 + k]);
}

// ---------------------------------------------------------------------------
// 3x3 conv, implicit GEMM via MFMA, K split into two 64-channel phases.
// Block = (2*NMT*16) oc x 64 px. 4 waves: wm = wid&1, wn = wid>>1.
// LDS: 3 rows x 66 w x 64 ch (28.5 KB) -> 3 blocks/CU; both phases' staging
// data prefetched into registers up front.
// MODE 0: +bias -> fp32 [B][HW][54]   MODE 1: +bias,BN,ReLU -> bf16 NHWC
// MODE 2: +bias,BN,+x(NCHW fp32),ReLU -> bf16 NHWC
// ---------------------------------------------------------------------------
template<int NMT, int MODE>
__global__ __launch_bounds__(256, 3) void conv3x3_mfma(
    const unsigned short* __restrict__ in, const unsigned short* __restrict__ wf,
    const float* __restrict__ bias, const float* __restrict__ bnp,
    const float* __restrict__ res, void* __restrict__ outv)
{
    __shared__ unsigned short sm[3][66][72];
    const int tid = threadIdx.x;
    const int lane = tid & 63, wid = tid >> 6;
    const int wm = wid & 1, wn = wid >> 1;
    const int w0 = (blockIdx.x & 1) * 64;
    const int h = blockIdx.x >> 1;
    const int b = blockIdx.y;
    const int n16 = lane & 15, quad = lane >> 4;

    // prefetch both 64-ch halves: 1584 16B-chunks each (3 rows x 66 w x 8)
    short8 L0[7], L1[7];
#pragma unroll
    for (int half = 0; half < 2; ++half) {
        short8* L = half ? L1 : L0;
#pragma unroll
        for (int rnd = 0; rnd < 7; ++rnd) {
            int idx = rnd * 256 + tid;
            short8 v = {0, 0, 0, 0, 0, 0, 0, 0};
            if (idx < 1584) {
                int c8 = idx & 7;
                int wl = (idx >> 3) % 66;
                int r  = (idx >> 3) / 66;
                int hh = h - 1 + r, ww = w0 - 1 + wl;
                if ((unsigned)hh < 128u && (unsigned)ww < 128u)
                    v = *(const short8*)&in[(((size_t)b << 14) + hh * 128 + ww) * 128 + half * 64 + c8 * 8];
            }
            L[rnd] = v;
        }
    }

    floatx4 acc[NMT][2];
#pragma unroll
    for (int mt = 0; mt < NMT; ++mt)
#pragma unroll
        for (int nt = 0; nt < 2; ++nt)
            acc[mt][nt] = (floatx4){0.f, 0.f, 0.f, 0.f};

#pragma unroll
    for (int half = 0; half < 2; ++half) {
        if (half) __syncthreads();   // all waves done reading phase-0 LDS
        {
            short8* L = half ? L1 : L0;
#pragma unroll
            for (int rnd = 0; rnd < 7; ++rnd) {
                int idx = rnd * 256 + tid;
                if (idx < 1584) {
                    int c8 = idx & 7;
                    int wl = (idx >> 3) % 66;
                    int r  = (idx >> 3) / 66;
                    *(short8*)&sm[r][wl][c8 * 8] = L[rnd];
                }
            }
        }
        __syncthreads();

#pragma unroll
        for (int tap = 0; tap < 9; ++tap) {
            const int ky = tap / 3, kx = tap % 3;
#pragma unroll
            for (int cc = 0; cc < 2; ++cc) {
                const int step = half * 18 + tap * 2 + cc;
                short8 a[NMT], bf[2];
#pragma unroll
                for (int nt = 0; nt < 2; ++nt)
                    bf[nt] = *(const short8*)&sm[ky][wn * 32 + nt * 16 + n16 + kx][cc * 32 + quad * 8];
#pragma unroll
                for (int mt = 0; mt < NMT; ++mt)
                    a[mt] = *(const short8*)&wf[((size_t)(step * (2 * NMT) + wm * NMT + mt) * 64 + lane) * 8];
#pragma unroll
                for (int mt = 0; mt < NMT; ++mt)
#pragma unroll
                    for (int nt = 0; nt < 2; ++nt)
                        acc[mt][nt] = __builtin_amdgcn_mfma_f32_16x16x32_bf16(a[mt], bf[nt], acc[mt][nt], 0, 0, 0);
            }
        }
    }

    // epilogue
#pragma unroll
    for (int mt = 0; mt < NMT; ++mt) {
        const int ocb = (wm * NMT + mt) * 16 + quad * 4;
        float Ae[4], Be[4];
#pragma unroll
        for (int r = 0; r < 4; ++r) {
            int oc = ocb + r;
            if (MODE == 0) {
                Ae[r] = 1.f;
                Be[r] = (oc < 54) ? bias[oc] : 0.f;
            } else {
                float g = bnp[oc], be = bnp[128 + oc], m = bnp[256 + oc], vv = bnp[384 + oc];
                float inv = g * rsqrtf(vv + EPSV);
                Ae[r] = inv;
                Be[r] = be - m * inv + bias[oc] * inv;
            }
        }
#pragma unroll
        for (int nt = 0; nt < 2; ++nt) {
            int pxg = h * 128 + w0 + wn * 32 + nt * 16 + n16;
            if (MODE == 0) {
                float* outf = (float*)outv;
#pragma unroll
                for (int r = 0; r < 4; ++r) {
                    int oc = ocb + r;
                    if (oc < 54)
                        outf[((size_t)(b << 14) + pxg) * 54 + oc] = acc[mt][nt][r] + Be[r];
                }
            } else {
                ushort4v pk;
#pragma unroll
                for (int r = 0; r < 4; ++r) {
                    float v = acc[mt][nt][r] * Ae[r] + Be[r];
                    if (MODE == 2) v += res[(((size_t)b * 128 + ocb + r) << 14) + pxg];
                    v = fmaxf(v, 0.f);
                    pk[r] = f2b(v);
                }
                *(ushort4v*)&((unsigned short*)outv)[((size_t)((b << 14) + pxg)) * 128 + ocb] = pk;
            }
        }
    }
}

// ---------------------------------------------------------------------------
// Fused modulated deformable conv, coalesced gather + software pipeline.
// Gather role: lane-group of 8 = 8 contiguous 16B chunks of one (px, corner)
// 64-ch row (exactly one 128B cacheline). Each thread owns 2 px x 4 corners.
// Double-buffered LDS tile; gathers for dk+1 issued before MFMA of dk.
// Block = 128 oc x 64 px; K = 18 dk * 64 c = 36 steps.
// ---------------------------------------------------------------------------
__global__ __launch_bounds__(256, 3) void deform_mfma(
    const unsigned short* __restrict__ src, const float* __restrict__ off,
    const unsigned short* __restrict__ wf, const float* __restrict__ dcb,
    const float* __restrict__ bnp, unsigned short* __restrict__ out)
{
    __shared__ unsigned short gt[2][64][72];
    const int tid = threadIdx.x;
    const int lane = tid & 63, wid = tid >> 6;
    const int wm = wid & 1, wn = wid >> 1;
    const int w0 = (blockIdx.x & 1) * 64;
    const int h = blockIdx.x >> 1;
    const int b = blockIdx.y;
    const int n16 = lane & 15, quad = lane >> 4;

    const int q = tid & 7;          // 16B chunk within 64-ch row
    const int pxq = tid >> 3;       // 0..31, pixel (phase ph adds 32)

    const float* offbase = off + ((size_t)(b << 14) + h * 128 + w0) * 54;
    const unsigned short* srcb = src + ((size_t)b << 21);

    floatx4 acc[4][2];
#pragma unroll
    for (int mt = 0; mt < 4; ++mt)
#pragma unroll
        for (int nt = 0; nt < 2; ++nt)
            acc[mt][nt] = (floatx4){0.f, 0.f, 0.f, 0.f};

    short8 g[2][4];     // [ph][corner 00,01,10,11]
    float  wA[2][4];    // blend weights
    float  oN[2][3];    // prefetched offsets (dk+2)
    float  oC[2][3];    // offsets for the gather being issued

    auto load_off = [&](int dk, float o[2][3]) {
#pragma unroll
        for (int ph = 0; ph < 2; ++ph) {
            const float* p = offbase + (size_t)(ph * 32 + pxq) * 54;
            o[ph][0] = p[2 * dk];
            o[ph][1] = p[2 * dk + 1];
            o[ph][2] = p[36 + dk];
        }
    };

    auto issue_gather = [&](int dk, const float o[2][3]) {
        const int d = (dk >= 9) ? 1 : 0;
        const int kk = dk - d * 9;
        const int choff = d * 64 + q * 8;
#pragma unroll
        for (int ph = 0; ph < 2; ++ph) {
            int px = ph * 32 + pxq;
            float ms = 1.f / (1.f + __expf(-o[ph][2]));
            float py = o[ph][0] + (float)h + (float)(kk / 3 - 1);
            float pxs = o[ph][1] + (float)(w0 + px) + (float)(kk % 3 - 1);
            float y0f = floorf(py), x0f = floorf(pxs);
            float fy = py - y0f, fx = pxs - x0f;
            int y0 = (int)y0f, x0 = (int)x0f;
            int y1 = y0 + 1, x1 = x0 + 1;
            float w00 = (1.f - fy) * (1.f - fx) * ms, w01 = (1.f - fy) * fx * ms;
            float w10 = fy * (1.f - fx) * ms, w11 = fy * fx * ms;
            if ((unsigned)y0 >= 128u) { w00 = 0.f; w01 = 0.f; }
            if ((unsigned)y1 >= 128u) { w10 = 0.f; w11 = 0.f; }
            if ((unsigned)x0 >= 128u) { w00 = 0.f; w10 = 0.f; }
            if ((unsigned)x1 >= 128u) { w01 = 0.f; w11 = 0.f; }
            wA[ph][0] = w00; wA[ph][1] = w01; wA[ph][2] = w10; wA[ph][3] = w11;
            int y0c = min(max(y0, 0), 127), y1c = min(max(y1, 0), 127);
            int x0c = min(max(x0, 0), 127), x1c = min(max(x1, 0), 127);
            g[ph][0] = *(const short8*)(srcb + (((size_t)(y0c * 128 + x0c)) << 7) + choff);
            g[ph][1] = *(const short8*)(srcb + (((size_t)(y0c * 128 + x1c)) << 7) + choff);
            g[ph][2] = *(const short8*)(srcb + (((size_t)(y1c * 128 + x0c)) << 7) + choff);
            g[ph][3] = *(const short8*)(srcb + (((size_t)(y1c * 128 + x1c)) << 7) + choff);
        }
    };

    // prologue
    load_off(0, oC);
    issue_gather(0, oC);
    load_off(1, oN);

    int buf = 0;
    for (int dk = 0; dk < 18; ++dk) {
        // blend prefetched corners -> LDS tile
#pragma unroll
        for (int ph = 0; ph < 2; ++ph) {
            short8 o8;
#pragma unroll
            for (int j = 0; j < 8; ++j) {
                float v = wA[ph][0] * b2f((unsigned short)g[ph][0][j])
                        + wA[ph][1] * b2f((unsigned short)g[ph][1][j])
                        + wA[ph][2] * b2f((unsigned short)g[ph][2][j])
                        + wA[ph][3] * b2f((unsigned short)g[ph][3][j]);
                o8[j] = (short)f2b(v);
            }
            *(short8*)&gt[buf][ph * 32 + pxq][q * 8] = o8;
        }
        __syncthreads();

        // issue next gather while MFMA runs on this tile
        if (dk < 17) {
#pragma unroll
            for (int ph = 0; ph < 2; ++ph)
#pragma unroll
                for (int j = 0; j < 3; ++j) oC[ph][j] = oN[ph][j];
            if (dk < 16) load_off(dk + 2, oN);
            issue_gather(dk + 1, oC);
        }

#pragma unroll
        for (int hf = 0; hf < 2; ++hf) {
            int s = dk * 2 + hf;
            short8 a[4], bfr[2];
#pragma unroll
            for (int nt = 0; nt < 2; ++nt)
                bfr[nt] = *(const short8*)&gt[buf][wn * 32 + nt * 16 + n16][hf * 32 + quad * 8];
#pragma unroll
            for (int mt = 0; mt < 4; ++mt)
                a[mt] = *(const short8*)&wf[((size_t)(s * 8 + wm * 4 + mt) * 64 + lane) * 8];
#pragma unroll
            for (int mt = 0; mt < 4; ++mt)
#pragma unroll
                for (int nt = 0; nt < 2; ++nt)
                    acc[mt][nt] = __builtin_amdgcn_mfma_f32_16x16x32_bf16(a[mt], bfr[nt], acc[mt][nt], 0, 0, 0);
        }
        buf ^= 1;
    }

#pragma unroll
    for (int mt = 0; mt < 4; ++mt) {
        const int ocb = (wm * 4 + mt) * 16 + quad * 4;
        float Ae[4], Be[4];
#pragma unroll
        for (int r = 0; r < 4; ++r) {
            int oc = ocb + r;
            float gg = bnp[oc], be = bnp[128 + oc], m = bnp[256 + oc], vv = bnp[384 + oc];
            float inv = gg * rsqrtf(vv + EPSV);
            Ae[r] = inv;
            Be[r] = be - m * inv + dcb[oc] * inv;
        }
#pragma unroll
        for (int nt = 0; nt < 2; ++nt) {
            int pxg2 = h * 128 + w0 + wn * 32 + nt * 16 + n16;
            ushort4v pk;
#pragma unroll
            for (int r = 0; r < 4; ++r) {
                float v = acc[mt][nt][r] * Ae[r] + Be[r];
                v = (v > 0.f) ? v : 0.1f * v;
                pk[r] = f2b(v);
            }
            *(ushort4v*)&out[((size_t)((b << 14) + pxg2)) * 128 + ocb] = pk;
        }
    }
}

// ---------------------------------------------------------------------------
// 1x1 conv GEMM (K=128, B-frags straight from global NHWC) + BN(bn2) +
// LeakyReLU + residual x -> fp32 NCHW d_out.
// ---------------------------------------------------------------------------
__global__ __launch_bounds__(256, 4) void conv1x1_mfma(
    const unsigned short* __restrict__ in, const unsigned short* __restrict__ wf,
    const float* __restrict__ bnp, const float* __restrict__ x, float* __restrict__ out)
{
    const int tid = threadIdx.x;
    const int lane = tid & 63, wid = tid >> 6;
    const int wm = wid & 1, wn = wid >> 1;
    const int w0 = (blockIdx.x & 1) * 64;
    const int h = blockIdx.x >> 1;
    const int b = blockIdx.y;
    const int n16 = lane & 15, quad = lane >> 4;

    floatx4 acc[4][2];
#pragma unroll
    for (int mt = 0; mt < 4; ++mt)
#pragma unroll
        for (int nt = 0; nt < 2; ++nt)
            acc[mt][nt] = (floatx4){0.f, 0.f, 0.f, 0.f};

#pragma unroll
    for (int s = 0; s < 4; ++s) {
        short8 a[4], bfr[2];
#pragma unroll
        for (int nt = 0; nt < 2; ++nt) {
            int px = h * 128 + w0 + wn * 32 + nt * 16 + n16;
            bfr[nt] = *(const short8*)&in[((size_t)((b << 14) + px)) * 128 + s * 32 + quad * 8];
        }
#pragma unroll
        for (int mt = 0; mt < 4; ++mt)
            a[mt] = *(const short8*)&wf[((size_t)(s * 8 + wm * 4 + mt) * 64 + lane) * 8];
#pragma unroll
        for (int mt = 0; mt < 4; ++mt)
#pragma unroll
            for (int nt = 0; nt < 2; ++nt)
                acc[mt][nt] = __builtin_amdgcn_mfma_f32_16x16x32_bf16(a[mt], bfr[nt], acc[mt][nt], 0, 0, 0);
    }

#pragma unroll
    for (int mt = 0; mt < 4; ++mt) {
        const int ocb = (wm * 4 + mt) * 16 + quad * 4;
        float Ae[4], Be[4];
#pragma unroll
        for (int r = 0; r < 4; ++r) {
            int oc = ocb + r;
            float g = bnp[oc], be = bnp[128 + oc], m = bnp[256 + oc], vv = bnp[384 + oc];
            float inv = g * rsqrtf(vv + EPSV);
            Ae[r] = inv;
            Be[r] = be - m * inv;
        }
#pragma unroll
        for (int nt = 0; nt < 2; ++nt) {
            int pxg2 = h * 128 + w0 + wn * 32 + nt * 16 + n16;
#pragma unroll
            for (int r = 0; r < 4; ++r) {
                int oc = ocb + r;
                float v = acc[mt][nt][r] * Ae[r] + Be[r];
                v = (v > 0.f) ? v : 0.1f * v;
                v += x[(((size_t)b * 128 + oc) << 14) + pxg2];
                out[(((size_t)b * 128 + oc) << 14) + pxg2] = v;
            }
        }
    }
}

// ---------------------------------------------------------------------------
extern "C" void kernel_launch(void* const* d_in, const int* in_sizes, int n_in,
                              void* d_out, int out_size, void* d_ws, size_t ws_size,
                              hipStream_t stream) {
    const float* x      = (const float*)d_in[0];
    const float* rb_w1  = (const float*)d_in[1];
    const float* rb_b1  = (const float*)d_in[2];
    const float* rb_bn1 = (const float*)d_in[3];
    const float* rb_w2  = (const float*)d_in[4];
    const float* rb_b2  = (const float*)d_in[5];
    const float* rb_bn2 = (const float*)d_in[6];
    const float* off_w  = (const float*)d_in[7];
    const float* off_b  = (const float*)d_in[8];
    const float* dc_w   = (const float*)d_in[9];
    const float* dc_b   = (const float*)d_in[10];
    const float* bn1    = (const float*)d_in[11];
    const float* cv2_w  = (const float*)d_in[12];
    const float* bn2    = (const float*)d_in[13];

    char* base = (char*)d_ws;
    const size_t TSZ = (size_t)4 * 16384 * 128 * 2;       // 16.78 MB bf16 tensor
    unsigned short* xb = (unsigned short*)base;            // aliased later as h3
    unsigned short* h1 = (unsigned short*)(base + TSZ);    // aliased later as offb
    unsigned short* h2 = (unsigned short*)(base + 2 * TSZ);
    unsigned short* wf1 = (unsigned short*)(base + 3 * TSZ);
    unsigned short* wf2 = wf1 + 1152 * 128;
    unsigned short* wfO = wf2 + 1152 * 128;
    unsigned short* wfD = wfO + 1152 * 64;
    unsigned short* wfC = wfD + 1152 * 128;
    float* offb = (float*)h1;            // [B][HW][54] fp32, 14.16 MB <= TSZ
    unsigned short* h3 = xb;             // xb dead after conv1

    dim3 blk(256, 1, 1);
    dim3 grid(256, BB, 1);

    transpose_k<<<grid, blk, 0, stream>>>(x, xb);
    repack_conv_frag<128, 128><<<576, 256, 0, stream>>>(rb_w1, wf1);
    repack_conv_frag<128, 128><<<576, 256, 0, stream>>>(rb_w2, wf2);
    repack_conv_frag<64, 54><<<288, 256, 0, stream>>>(off_w, wfO);
    repack_dc_frag<<<576, 256, 0, stream>>>(dc_w, wfD);
    repack_cv2_frag<<<64, 256, 0, stream>>>(cv2_w, wfC);

    // ResBlock
    conv3x3_mfma<4, 1><<<grid, blk, 0, stream>>>(xb, wf1, rb_b1, rb_bn1, nullptr, (void*)h1);
    conv3x3_mfma<4, 2><<<grid, blk, 0, stream>>>(h1, wf2, rb_b2, rb_bn2, x, (void*)h2);
    // offset conv (writes over h1, which is dead)
    conv3x3_mfma<2, 0><<<grid, blk, 0, stream>>>(h2, wfO, off_b, nullptr, nullptr, (void*)offb);
    // fused modulated deformable conv + BN + LeakyReLU
    deform_mfma<<<grid, blk, 0, stream>>>(h2, offb, wfD, dc_b, bn1, h3);
    // 1x1 conv + BN + LeakyReLU + residual
    conv1x1_mfma<<<grid, blk, 0, stream>>>(h3, wfC, bn2, x, (float*)d_out);
}

// Round 4
// 275.512 us; speedup vs baseline: 8.1886x; 1.1053x over previous
//
#include <hip/hip_runtime.h>
#include <math.h>

#define BB 4
#define EPSV 1e-5f

typedef __attribute__((ext_vector_type(8))) short short8;
typedef __attribute__((ext_vector_type(4))) float floatx4;
typedef __attribute__((ext_vector_type(4))) int intx4;
typedef __attribute__((ext_vector_type(4))) unsigned short ushort4v;

__device__ inline float b2f(unsigned short u) {
    unsigned v = ((unsigned)u) << 16;
    return __builtin_bit_cast(float, v);
}
__device__ inline unsigned short f2b(float f) {   // RNE (for weights/activations)
    unsigned u = __builtin_bit_cast(unsigned, f);
    u += 0x7FFFu + ((u >> 16) & 1u);
    return (unsigned short)(u >> 16);
}
__device__ inline unsigned short f2b_fast(float f) {  // round-half-up, 2 inst
    unsigned u = __builtin_bit_cast(unsigned, f);
    return (unsigned short)((u + 0x8000u) >> 16);
}

// ---------------------------------------------------------------------------
// x [B][128 c][16384 px] fp32  ->  xb [B][16384 px][128 c] bf16  (NHWC)
// ---------------------------------------------------------------------------
__global__ __launch_bounds__(256) void transpose_k(const float* __restrict__ x,
                                                   unsigned short* __restrict__ xb) {
    __shared__ unsigned short t[64][136];
    const int tid = threadIdx.x;
    const int px0 = blockIdx.x * 64;
    const int b = blockIdx.y;
    const int pxr = tid & 63;
    const int c0 = tid >> 6;
#pragma unroll
    for (int i = 0; i < 32; ++i) {
        int c = c0 + i * 4;
        float v = x[(((size_t)b * 128 + c) << 14) + px0 + pxr];
        t[pxr][c] = f2b(v);
    }
    __syncthreads();
#pragma unroll
    for (int i = 0; i < 4; ++i) {
        int idx = tid + i * 256;
        int px = idx >> 4;
        int c8 = idx & 15;
        short8 v = *(const short8*)&t[px][c8 * 8];
        *(short8*)&xb[(((size_t)b << 14) + px0 + px) * 128 + c8 * 8] = v;
    }
}

// ---------------------------------------------------------------------------
// Weight repacks into MFMA A-fragment order:
// dst[((step*NMT2 + mt)*64 + lane)*8 + j] = W[oc = mt*16 + (lane&15)]
//                                            [k  = step*32 + (lane>>4)*8 + j]
// ---------------------------------------------------------------------------
// conv 3x3 (ch-split K order): k = half*576 + tap*64 + c64, src [OCH][128][9]
template<int MPAD, int OCH>
__global__ __launch_bounds__(256) void repack_conv_frag(const float* __restrict__ w,
                                                        unsigned short* __restrict__ dst) {
    int t = blockIdx.x * 256 + threadIdx.x;
    if (t >= 1152 * MPAD) return;
    const int NMT2 = MPAD / 16;
    int j = t & 7, lane = (t >> 3) & 63, rest = t >> 9;
    int mt = rest % NMT2, step = rest / NMT2;
    int oc = mt * 16 + (lane & 15);
    int k = step * 32 + ((lane >> 4) << 3) + j;
    int half = k / 576;
    int tap = (k - half * 576) >> 6;
    int c = half * 64 + (k & 63);
    float v = (oc < OCH) ? w[((size_t)oc * 128 + c) * 9 + tap] : 0.f;
    dst[t] = f2b(v);
}

// dc: k = dk*64 + c, dk = d*9+kk, src [128 oc][128 ci=d*64+c][9 kk]
__global__ __launch_bounds__(256) void repack_dc_frag(const float* __restrict__ w,
                                                      unsigned short* __restrict__ dst) {
    int t = blockIdx.x * 256 + threadIdx.x;
    if (t >= 1152 * 128) return;
    int j = t & 7, lane = (t >> 3) & 63, rest = t >> 9;
    int mt = rest & 7, step = rest >> 3;
    int oc = mt * 16 + (lane & 15);
    int k = step * 32 + ((lane >> 4) << 3) + j;
    int dk = k >> 6, c = k & 63;
    int d = (dk >= 9) ? 1 : 0;
    int kk = dk - d * 9;
    float v = w[((size_t)oc * 128 + d * 64 + c) * 9 + kk];
    dst[t] = f2b(v);
}

// cv2 1x1: k = c, src [128 oc][128 c]
__global__ __launch_bounds__(256) void repack_cv2_frag(const float* __restrict__ w,
                                                       unsigned short* __restrict__ dst) {
    int t = blockIdx.x * 256 + threadIdx.x;
    if (t >= 128 * 128) return;
    int j = t & 7, lane = (t >> 3) & 63, rest = t >> 9;
    int mt = rest & 7, step = rest >> 3;
    int oc = mt * 16 + (lane & 15);
    int k = step * 32 + ((lane >> 4) << 3) + j;
    dst[t] = f2b(w[oc * 128 + k]);
}

// ---------------------------------------------------------------------------
// 3x3 conv, implicit GEMM, 128-px (full row) x (NMT*32) oc tile.
// 4 waves in 2x2: wm = M-half, wn = N-half (64 px each). Per wave per K-step:
// NMT a-frags (global, L2-hot) + 4 b-frags (LDS) -> 4*NMT MFMA.
// K split in two 64-ch halves; half-1 staging prefetched into regs before
// half-0 compute. LDS: 3 rows x 130 w x 64 ch (54.8 KB) -> 2 blocks/CU.
// MODE 0: +bias -> fp32 NCHW [B][54][HW]   (offset conv, NMT=2)
// MODE 1: +bias,BN,ReLU -> bf16 NHWC
// MODE 2: +bias,BN,+x(NCHW fp32),ReLU -> bf16 NHWC
// ---------------------------------------------------------------------------
template<int NMT, int MODE>
__global__ __launch_bounds__(256, 2) void conv3x3_mfma(
    const unsigned short* __restrict__ in, const unsigned short* __restrict__ wf,
    const float* __restrict__ bias, const float* __restrict__ bnp,
    const float* __restrict__ res, void* __restrict__ outv)
{
    __shared__ unsigned short sm[3][130][72];
    const int tid = threadIdx.x;
    const int lane = tid & 63, wid = tid >> 6;
    const int wm = wid & 1, wn = wid >> 1;
    const int h = blockIdx.x;
    const int b = blockIdx.y;
    const int n16 = lane & 15, quad = lane >> 4;

    short8 L[13];

    auto stage_load = [&](int half) {
#pragma unroll
        for (int rnd = 0; rnd < 13; ++rnd) {
            int idx = rnd * 256 + tid;
            short8 v = {0, 0, 0, 0, 0, 0, 0, 0};
            if (idx < 3120) {
                int c8 = idx & 7;
                int wl = (idx >> 3) % 130;
                int r  = (idx >> 3) / 130;
                int hh = h - 1 + r, ww = wl - 1;
                if ((unsigned)hh < 128u && (unsigned)ww < 128u)
                    v = *(const short8*)&in[(((size_t)b << 14) + hh * 128 + ww) * 128 + half * 64 + c8 * 8];
            }
            L[rnd] = v;
        }
    };
    auto stage_write = [&]() {
#pragma unroll
        for (int rnd = 0; rnd < 13; ++rnd) {
            int idx = rnd * 256 + tid;
            if (idx < 3120) {
                int c8 = idx & 7;
                int wl = (idx >> 3) % 130;
                int r  = (idx >> 3) / 130;
                *(short8*)&sm[r][wl][c8 * 8] = L[rnd];
            }
        }
    };

    floatx4 acc[NMT][4];
#pragma unroll
    for (int mt = 0; mt < NMT; ++mt)
#pragma unroll
        for (int nt = 0; nt < 4; ++nt)
            acc[mt][nt] = (floatx4){0.f, 0.f, 0.f, 0.f};

    auto compute = [&](int half) {
#pragma unroll
        for (int tap = 0; tap < 9; ++tap) {
            const int ky = tap / 3, kx = tap % 3;
#pragma unroll
            for (int cc = 0; cc < 2; ++cc) {
                const int step = half * 18 + tap * 2 + cc;
                short8 a[NMT], bf[4];
#pragma unroll
                for (int nt = 0; nt < 4; ++nt)
                    bf[nt] = *(const short8*)&sm[ky][wn * 64 + nt * 16 + n16 + kx][cc * 32 + quad * 8];
#pragma unroll
                for (int mt = 0; mt < NMT; ++mt)
                    a[mt] = *(const short8*)&wf[((size_t)(step * (2 * NMT) + wm * NMT + mt) * 64 + lane) * 8];
#pragma unroll
                for (int mt = 0; mt < NMT; ++mt)
#pragma unroll
                    for (int nt = 0; nt < 4; ++nt)
                        acc[mt][nt] = __builtin_amdgcn_mfma_f32_16x16x32_bf16(a[mt], bf[nt], acc[mt][nt], 0, 0, 0);
            }
        }
    };

    stage_load(0);
    stage_write();
    __syncthreads();
    stage_load(1);       // VMEM in flight across half-0 compute
    compute(0);
    __syncthreads();     // all waves done reading half-0 LDS
    stage_write();
    __syncthreads();
    compute(1);

    // epilogue
#pragma unroll
    for (int mt = 0; mt < NMT; ++mt) {
        const int ocb = (wm * NMT + mt) * 16 + quad * 4;
        float Ae[4], Be[4];
#pragma unroll
        for (int r = 0; r < 4; ++r) {
            int oc = ocb + r;
            if (MODE == 0) {
                Ae[r] = 1.f;
                Be[r] = (oc < 54) ? bias[oc] : 0.f;
            } else {
                float g = bnp[oc], be = bnp[128 + oc], m = bnp[256 + oc], vv = bnp[384 + oc];
                float inv = g * rsqrtf(vv + EPSV);
                Ae[r] = inv;
                Be[r] = be - m * inv + bias[oc] * inv;
            }
        }
#pragma unroll
        for (int nt = 0; nt < 4; ++nt) {
            int pxg = h * 128 + wn * 64 + nt * 16 + n16;
            if (MODE == 0) {
                float* outf = (float*)outv;   // NCHW [B][54][HW]
#pragma unroll
                for (int r = 0; r < 4; ++r) {
                    int oc = ocb + r;
                    if (oc < 54)
                        outf[(((size_t)(b * 54 + oc)) << 14) + pxg] = acc[mt][nt][r] + Be[r];
                }
            } else {
                ushort4v pk;
#pragma unroll
                for (int r = 0; r < 4; ++r) {
                    float v = acc[mt][nt][r] * Ae[r] + Be[r];
                    if (MODE == 2) v += res[(((size_t)b * 128 + ocb + r) << 14) + pxg];
                    v = fmaxf(v, 0.f);
                    pk[r] = f2b(v);
                }
                *(ushort4v*)&((unsigned short*)outv)[((size_t)((b << 14) + pxg)) * 128 + ocb] = pk;
            }
        }
    }
}

// ---------------------------------------------------------------------------
// Fused modulated deformable conv.
// Sampling math deduplicated: wave 0 (tid<64, px=tid) computes per-px corner
// byte-offsets + blend weights once per dk -> triple-buffered LDS. Gather
// lanes (q=tid&7 chunk, pxq=tid>>3 px) ds_read them, fetch 4 coalesced 16B
// corner chunks, blend -> double-buffered LDS B-tile -> MFMA.
// offsets tensor is NCHW fp32 [B][54][HW] (coalesced plane loads).
// Block = 128 oc x 64 px; K = 18 dk * 64 c; 1 barrier/dk.
// ---------------------------------------------------------------------------
__global__ __launch_bounds__(256, 4) void deform_mfma(
    const unsigned short* __restrict__ src, const float* __restrict__ off,
    const unsigned short* __restrict__ wf, const float* __restrict__ dcb,
    const float* __restrict__ bnp, unsigned short* __restrict__ out)
{
    __shared__ unsigned short gt[2][64][72];   // 18 KB
    __shared__ floatx4 smw[3][64];             // 3 KB  blend weights
    __shared__ intx4   sma[3][64];             // 3 KB  corner byte offsets
    const int tid = threadIdx.x;
    const int lane = tid & 63, wid = tid >> 6;
    const int wm = wid & 1, wn = wid >> 1;
    const int w0 = (blockIdx.x & 1) * 64;
    const int h = blockIdx.x >> 1;
    const int b = blockIdx.y;
    const int n16 = lane & 15, quad = lane >> 4;
    const int q = tid & 7;
    const int pxq = tid >> 3 & 31;

    const char* srcbyte = (const char*)src + ((size_t)b << 22);
    const float* offpx = off + (((size_t)(b * 54)) << 14) + h * 128 + w0 + tid; // valid for tid<64

    // ---- sampling math for px = tid (tid < 64 only) ----
    auto math = [&](int dk, int slot) {
        float oy = offpx[(size_t)(2 * dk) << 14];
        float ox = offpx[(size_t)(2 * dk + 1) << 14];
        float mz = offpx[(size_t)(36 + dk) << 14];
        int d = (dk >= 9) ? 1 : 0;
        int kk = dk - d * 9;
        float ms = 1.f / (1.f + __expf(-mz));
        float py = oy + (float)h + (float)(kk / 3 - 1);
        float pxs = ox + (float)(w0 + tid) + (float)(kk % 3 - 1);
        float y0f = floorf(py), x0f = floorf(pxs);
        float fy = py - y0f, fx = pxs - x0f;
        int y0 = (int)y0f, x0 = (int)x0f;
        int y1 = y0 + 1, x1 = x0 + 1;
        float w00 = (1.f - fy) * (1.f - fx) * ms, w01 = (1.f - fy) * fx * ms;
        float w10 = fy * (1.f - fx) * ms, w11 = fy * fx * ms;
        if ((unsigned)y0 >= 128u) { w00 = 0.f; w01 = 0.f; }
        if ((unsigned)y1 >= 128u) { w10 = 0.f; w11 = 0.f; }
        if ((unsigned)x0 >= 128u) { w00 = 0.f; w10 = 0.f; }
        if ((unsigned)x1 >= 128u) { w01 = 0.f; w11 = 0.f; }
        int y0c = min(max(y0, 0), 127), y1c = min(max(y1, 0), 127);
        int x0c = min(max(x0, 0), 127), x1c = min(max(x1, 0), 127);
        int chb = d * 128;
        smw[slot][tid] = (floatx4){w00, w01, w10, w11};
        sma[slot][tid] = (intx4){((y0c * 128 + x0c) << 8) + chb, ((y0c * 128 + x1c) << 8) + chb,
                                 ((y1c * 128 + x0c) << 8) + chb, ((y1c * 128 + x1c) << 8) + chb};
    };

    floatx4 wA[2];
    short8 g[2][4];
    auto gather = [&](int slot) {
#pragma unroll
        for (int ph = 0; ph < 2; ++ph) {
            int pxl = ph * 32 + pxq;
            floatx4 wv = smw[slot][pxl];
            intx4 av = sma[slot][pxl];
            wA[ph] = wv;
#pragma unroll
            for (int c = 0; c < 4; ++c)
                g[ph][c] = *(const short8*)(srcbyte + (size_t)(av[c] + q * 16));
        }
    };

    floatx4 acc[4][2];
#pragma unroll
    for (int mt = 0; mt < 4; ++mt)
#pragma unroll
        for (int nt = 0; nt < 2; ++nt)
            acc[mt][nt] = (floatx4){0.f, 0.f, 0.f, 0.f};

    if (tid < 64) { math(0, 0); math(1, 1); }
    __syncthreads();
    gather(0);

    int buf = 0;
    for (int dk = 0; dk < 18; ++dk) {
        // blend prefetched corners -> LDS B-tile
#pragma unroll
        for (int ph = 0; ph < 2; ++ph) {
            short8 o8;
#pragma unroll
            for (int j = 0; j < 8; ++j) {
                float v = wA[ph][0] * b2f((unsigned short)g[ph][0][j])
                        + wA[ph][1] * b2f((unsigned short)g[ph][1][j])
                        + wA[ph][2] * b2f((unsigned short)g[ph][2][j])
                        + wA[ph][3] * b2f((unsigned short)g[ph][3][j]);
                o8[j] = (short)f2b_fast(v);
            }
            *(short8*)&gt[buf][ph * 32 + pxq][q * 8] = o8;
        }
        if (tid < 64 && dk < 16) math(dk + 2, (dk + 2) % 3);
        __syncthreads();
        if (dk < 17) gather((dk + 1) % 3);

#pragma unroll
        for (int hf = 0; hf < 2; ++hf) {
            int s = dk * 2 + hf;
            short8 a[4], bfr[2];
#pragma unroll
            for (int nt = 0; nt < 2; ++nt)
                bfr[nt] = *(const short8*)&gt[buf][wn * 32 + nt * 16 + n16][hf * 32 + quad * 8];
#pragma unroll
            for (int mt = 0; mt < 4; ++mt)
                a[mt] = *(const short8*)&wf[((size_t)(s * 8 + wm * 4 + mt) * 64 + lane) * 8];
#pragma unroll
            for (int mt = 0; mt < 4; ++mt)
#pragma unroll
                for (int nt = 0; nt < 2; ++nt)
                    acc[mt][nt] = __builtin_amdgcn_mfma_f32_16x16x32_bf16(a[mt], bfr[nt], acc[mt][nt], 0, 0, 0);
        }
        buf ^= 1;
    }

#pragma unroll
    for (int mt = 0; mt < 4; ++mt) {
        const int ocb = (wm * 4 + mt) * 16 + quad * 4;
        float Ae[4], Be[4];
#pragma unroll
        for (int r = 0; r < 4; ++r) {
            int oc = ocb + r;
            float gg = bnp[oc], be = bnp[128 + oc], m = bnp[256 + oc], vv = bnp[384 + oc];
            float inv = gg * rsqrtf(vv + EPSV);
            Ae[r] = inv;
            Be[r] = be - m * inv + dcb[oc] * inv;
        }
#pragma unroll
        for (int nt = 0; nt < 2; ++nt) {
            int pxg2 = h * 128 + w0 + wn * 32 + nt * 16 + n16;
            ushort4v pk;
#pragma unroll
            for (int r = 0; r < 4; ++r) {
                float v = acc[mt][nt][r] * Ae[r] + Be[r];
                v = (v > 0.f) ? v : 0.1f * v;
                pk[r] = f2b(v);
            }
            *(ushort4v*)&out[((size_t)((b << 14) + pxg2)) * 128 + ocb] = pk;
        }
    }
}

// ---------------------------------------------------------------------------
// 1x1 conv GEMM (K=128, B-frags straight from global NHWC) + BN(bn2) +
// LeakyReLU + residual x -> fp32 NCHW d_out.
// ---------------------------------------------------------------------------
__global__ __launch_bounds__(256, 4) void conv1x1_mfma(
    const unsigned short* __restrict__ in, const unsigned short* __restrict__ wf,
    const float* __restrict__ bnp, const float* __restrict__ x, float* __restrict__ out)
{
    const int tid = threadIdx.x;
    const int lane = tid & 63, wid = tid >> 6;
    const int wm = wid & 1, wn = wid >> 1;
    const int w0 = (blockIdx.x & 1) * 64;
    const int h = blockIdx.x >> 1;
    const int b = blockIdx.y;
    const int n16 = lane & 15, quad = lane >> 4;

    floatx4 acc[4][2];
#pragma unroll
    for (int mt = 0; mt < 4; ++mt)
#pragma unroll
        for (int nt = 0; nt < 2; ++nt)
            acc[mt][nt] = (floatx4){0.f, 0.f, 0.f, 0.f};

#pragma unroll
    for (int s = 0; s < 4; ++s) {
        short8 a[4], bfr[2];
#pragma unroll
        for (int nt = 0; nt < 2; ++nt) {
            int px = h * 128 + w0 + wn * 32 + nt * 16 + n16;
            bfr[nt] = *(const short8*)&in[((size_t)((b << 14) + px)) * 128 + s * 32 + quad * 8];
        }
#pragma unroll
        for (int mt = 0; mt < 4; ++mt)
            a[mt] = *(const short8*)&wf[((size_t)(s * 8 + wm * 4 + mt) * 64 + lane) * 8];
#pragma unroll
        for (int mt = 0; mt < 4; ++mt)
#pragma unroll
            for (int nt = 0; nt < 2; ++nt)
                acc[mt][nt] = __builtin_amdgcn_mfma_f32_16x16x32_bf16(a[mt], bfr[nt], acc[mt][nt], 0, 0, 0);
    }

#pragma unroll
    for (int mt = 0; mt < 4; ++mt) {
        const int ocb = (wm * 4 + mt) * 16 + quad * 4;
        float Ae[4], Be[4];
#pragma unroll
        for (int r = 0; r < 4; ++r) {
            int oc = ocb + r;
            float g = bnp[oc], be = bnp[128 + oc], m = bnp[256 + oc], vv = bnp[384 + oc];
            float inv = g * rsqrtf(vv + EPSV);
            Ae[r] = inv;
            Be[r] = be - m * inv;
        }
#pragma unroll
        for (int nt = 0; nt < 2; ++nt) {
            int pxg2 = h * 128 + w0 + wn * 32 + nt * 16 + n16;
#pragma unroll
            for (int r = 0; r < 4; ++r) {
                int oc = ocb + r;
                float v = acc[mt][nt][r] * Ae[r] + Be[r];
                v = (v > 0.f) ? v : 0.1f * v;
                v += x[(((size_t)b * 128 + oc) << 14) + pxg2];
                out[(((size_t)b * 128 + oc) << 14) + pxg2] = v;
            }
        }
    }
}

// ---------------------------------------------------------------------------
extern "C" void kernel_launch(void* const* d_in, const int* in_sizes, int n_in,
                              void* d_out, int out_size, void* d_ws, size_t ws_size,
                              hipStream_t stream) {
    const float* x      = (const float*)d_in[0];
    const float* rb_w1  = (const float*)d_in[1];
    const float* rb_b1  = (const float*)d_in[2];
    const float* rb_bn1 = (const float*)d_in[3];
    const float* rb_w2  = (const float*)d_in[4];
    const float* rb_b2  = (const float*)d_in[5];
    const float* rb_bn2 = (const float*)d_in[6];
    const float* off_w  = (const float*)d_in[7];
    const float* off_b  = (const float*)d_in[8];
    const float* dc_w   = (const float*)d_in[9];
    const float* dc_b   = (const float*)d_in[10];
    const float* bn1    = (const float*)d_in[11];
    const float* cv2_w  = (const float*)d_in[12];
    const float* bn2    = (const float*)d_in[13];

    char* base = (char*)d_ws;
    const size_t TSZ = (size_t)4 * 16384 * 128 * 2;       // 16.78 MB bf16 tensor
    unsigned short* xb = (unsigned short*)base;            // aliased later as h3
    unsigned short* h1 = (unsigned short*)(base + TSZ);    // aliased later as offb
    unsigned short* h2 = (unsigned short*)(base + 2 * TSZ);
    unsigned short* wf1 = (unsigned short*)(base + 3 * TSZ);
    unsigned short* wf2 = wf1 + 1152 * 128;
    unsigned short* wfO = wf2 + 1152 * 128;
    unsigned short* wfD = wfO + 1152 * 64;
    unsigned short* wfC = wfD + 1152 * 128;
    float* offb = (float*)h1;            // NCHW fp32 [B][54][HW], 14.16 MB <= TSZ
    unsigned short* h3 = xb;             // xb dead after conv1

    dim3 blk(256, 1, 1);
    dim3 grid(256, BB, 1);
    dim3 grid3(128, BB, 1);

    transpose_k<<<grid, blk, 0, stream>>>(x, xb);
    repack_conv_frag<128, 128><<<576, 256, 0, stream>>>(rb_w1, wf1);
    repack_conv_frag<128, 128><<<576, 256, 0, stream>>>(rb_w2, wf2);
    repack_conv_frag<64, 54><<<288, 256, 0, stream>>>(off_w, wfO);
    repack_dc_frag<<<576, 256, 0, stream>>>(dc_w, wfD);
    repack_cv2_frag<<<64, 256, 0, stream>>>(cv2_w, wfC);

    // ResBlock
    conv3x3_mfma<4, 1><<<grid3, blk, 0, stream>>>(xb, wf1, rb_b1, rb_bn1, nullptr, (void*)h1);
    conv3x3_mfma<4, 2><<<grid3, blk, 0, stream>>>(h1, wf2, rb_b2, rb_bn2, x, (void*)h2);
    // offset conv -> NCHW fp32 (writes over h1, which is dead)
    conv3x3_mfma<2, 0><<<grid3, blk, 0, stream>>>(h2, wfO, off_b, nullptr, nullptr, (void*)offb);
    // fused modulated deformable conv + BN + LeakyReLU
    deform_mfma<<<grid, blk, 0, stream>>>(h2, offb, wfD, dc_b, bn1, h3);
    // 1x1 conv + BN + LeakyReLU + residual
    conv1x1_mfma<<<grid, blk, 0, stream>>>(h3, wfC, bn2, x, (float*)d_out);
}